// Round 6
// baseline (902.264 us; speedup 1.0000x reference)
//
#include <hip/hip_runtime.h>
#include <hip/hip_cooperative_groups.h>

namespace cg = cooperative_groups;

#define NN 4096
#define MM 8192
#define GG 8
#define HH 128
#define NDD 16
#define EE 131072
#define CBLK 64            // cond partial blocks
#define COBJ (MM / CBLK)   // 128 objects per cond block
#define GRID 1024

typedef float nt_f4 __attribute__((ext_vector_type(4)));

struct Prm {
    const float* x;
    const int* e_src;
    const int* e_dst;
    const int* timestep;
    const int* bm;
    const int* nuc;
    const int* central;
    const int* backbone;
    const float* obj_x;
    const float* obj_pos;
    const int* obj_batch;
    const float* Wn; const float* bn;
    const float* Wt; const float* bt;
    const float* Wc; const float* bc;
    const float* Wc1; const float* b1;
    const float* Wc2; const float* b2;
    const float* Wo; const float* bo;
    const float* we; const float* be;
    float* bufA; float* bufB;
    float* W1p; float* c1;
    float* partial; float* pcnt;
    float* dinv; float* sl; float* sr;
    int* deg; int* row_ptr; int* cursor; int* col_idx;
    float* out_pred; float* out_edges;
};

__global__ __launch_bounds__(256, 4) void mega(Prm p) {
    cg::grid_group grid = cg::this_grid();
    int b = blockIdx.x, t = threadIdx.x;
    __shared__ float sm[1728];  // overlaid per phase (max: c1 phase 1672 floats)

    // ================= P0: zero deg | cond partials | W1p =================
    if (b < 16) {
        p.deg[b * 256 + t] = 0;
    } else if (b < 16 + CBLK) {
        int cb = b - 16;
        float* ls = sm;            // GG*NDD = 128
        float* lc = sm + GG * NDD; // GG
        if (t < GG * NDD) ls[t] = 0.f;
        if (t < GG) lc[t] = 0.f;
        __syncthreads();
        int d = t & 15, oi = t >> 4;
        int base = cb * COBJ;
#pragma unroll
        for (int pass = 0; pass < COBJ / 16; pass++) {
            int o = base + pass * 16 + oi;
            int nv = p.nuc[o];
            bool isb = (p.backbone[o] == 0);
            bool cond = (nv == 0) || ((p.central[o] != 0) && isb) || ((nv == 2) && isb);
            if (cond) {
                float v = (d < 13) ? p.obj_x[o * 13 + d] : p.obj_pos[o * 3 + (d - 13)];
                int g = p.obj_batch[o];
                atomicAdd(&ls[g * NDD + d], v);
                if (d == 0) atomicAdd(&lc[g], 1.f);
            }
        }
        __syncthreads();
        if (t < GG * NDD) p.partial[cb * (GG * NDD) + t] = ls[t];
        if (t < GG) p.pcnt[cb * GG + t] = lc[t];
    } else if (b < 16 + CBLK + 16) {
        int a = b - (16 + CBLK);  // W1p row a
        if (t < HH) {
            float acc = 0.f;
            for (int k = 0; k < HH; k++) acc += p.Wn[a * HH + k] * p.Wc1[k * HH + t];
            p.W1p[a * HH + t] = acc;
        }
    }
    grid.sync();

    // ====== P1: c1 (blocks 0, 641) | deg count (1..128) | xw1_partial (129..640) ======
    if (b == 0 || b == 641) {
        int ghalf = (b == 0) ? 0 : 1;
        float* te = sm;            // 512
        float* pool = sm + 512;    // 512
        float* v2 = sm + 1024;     // 512
        float* s16 = sm + 1536;    // 128
        float* cinv = sm + 1664;   // 8
        if (t < GG * NDD) {
            float s = 0.f;
            for (int q = 0; q < CBLK; q++) s += p.partial[q * (GG * NDD) + t];
            s16[t] = s;
        }
        if (t < GG) {
            float c = 0.f;
            for (int q = 0; q < CBLK; q++) c += p.pcnt[q * GG + t];
            cinv[t] = 1.f / fmaxf(c, 1.f);
        }
        __syncthreads();
        int j = t & 127, gsub = t >> 7;
#pragma unroll
        for (int gi = 0; gi < 2; gi++) {
            int gl = gsub * 2 + gi;          // local g 0..3
            int g = ghalf * 4 + gl;          // global g
            float tv = (float)p.timestep[g];
            float val;
            if (j < 64) {
                float f = expf(-logf(10000.f) * (float)j / 64.f);
                val = cosf(tv * f);
            } else {
                float f = expf(-logf(10000.f) * (float)(j - 64) / 64.f);
                val = sinf(tv * f);
            }
            te[gl * HH + j] = val;
            float pv = p.bn[j];
#pragma unroll
            for (int d = 0; d < NDD; d++)
                pv += s16[g * NDD + d] * cinv[g] * p.Wn[d * HH + j];
            pool[gl * HH + j] = pv;
        }
        __syncthreads();
#pragma unroll
        for (int gi = 0; gi < 2; gi++) {
            int gl = gsub * 2 + gi;
            float acc = p.bt[j] + p.bc[j] + p.bn[j];
            for (int k = 0; k < HH; k++) {
                acc += te[gl * HH + k] * p.Wt[k * HH + j] + pool[gl * HH + k] * p.Wc[k * HH + j];
            }
            v2[gl * HH + j] = acc;
        }
        __syncthreads();
#pragma unroll
        for (int gi = 0; gi < 2; gi++) {
            int gl = gsub * 2 + gi;
            int g = ghalf * 4 + gl;
            float cc = 0.f;
            for (int k = 0; k < HH; k++) cc += v2[gl * HH + k] * p.Wc1[k * HH + j];
            p.c1[g * HH + j] = cc;
        }
    } else if (b <= 128) {
        int4 d4 = ((const int4*)p.e_dst)[(b - 1) * 256 + t];
        atomicAdd(&p.deg[d4.x], 1);
        atomicAdd(&p.deg[d4.y], 1);
        atomicAdd(&p.deg[d4.z], 1);
        atomicAdd(&p.deg[d4.w], 1);
    } else if (b < 641) {
        // xw1_partial = x @ W1p (no c1/dinv yet)
        float* xt = sm;  // 128
        int r0 = (b - 129) * 8;
        if (t < 128) xt[t] = p.x[r0 * NDD + t];
        __syncthreads();
        int col = t & 127, rh = t >> 7;
#pragma unroll
        for (int i = 0; i < 4; i++) {
            int r = rh * 4 + i;
            float acc = 0.f;
#pragma unroll
            for (int k = 0; k < NDD; k++) acc += xt[r * NDD + k] * p.W1p[k * HH + col];
            p.bufA[(r0 + r) * HH + col] = acc;
        }
    }
    grid.sync();

    // ================= P2: scan (block 0, 16 elems/thread) =================
    if (b == 0) {
        int* aux = (int*)sm;
        int d[16];
        int base_i = t * 16;
        int s = 0;
#pragma unroll
        for (int ii = 0; ii < 4; ii++) {
            int4 v = ((const int4*)(p.deg + base_i))[ii];
            d[4 * ii] = v.x; d[4 * ii + 1] = v.y; d[4 * ii + 2] = v.z; d[4 * ii + 3] = v.w;
            s += v.x + v.y + v.z + v.w;
        }
        aux[t] = s;
        __syncthreads();
        for (int off = 1; off < 256; off <<= 1) {
            int v = (t >= off) ? aux[t - off] : 0;
            __syncthreads();
            aux[t] += v;
            __syncthreads();
        }
        int run = (t > 0) ? aux[t - 1] : 0;
#pragma unroll
        for (int i = 0; i < 16; i++) {
            int idx = base_i + i;
            p.row_ptr[idx] = run;
            p.cursor[idx] = run;
            p.dinv[idx] = rsqrtf((float)(d[i] + 1));  // +1: self loop
            run += d[i];
        }
        if (t == 255) p.row_ptr[NN] = run;
    }
    grid.sync();

    // ================= P3: scatter (0..127) | xw1 fixup (128..639) =================
    if (b < 128) {
        int i4 = b * 256 + t;
        int4 d4 = ((const int4*)p.e_dst)[i4];
        int4 s4 = ((const int4*)p.e_src)[i4];
        int q;
        q = atomicAdd(&p.cursor[d4.x], 1); p.col_idx[q] = s4.x;
        q = atomicAdd(&p.cursor[d4.y], 1); p.col_idx[q] = s4.y;
        q = atomicAdd(&p.cursor[d4.z], 1); p.col_idx[q] = s4.z;
        q = atomicAdd(&p.cursor[d4.w], 1); p.col_idx[q] = s4.w;
    } else if (b < 640) {
        int r0 = (b - 128) * 8;
        int col = t & 127, rh = t >> 7;
#pragma unroll
        for (int i = 0; i < 4; i++) {
            int row = r0 + rh * 4 + i;
            float v = (p.bufA[row * HH + col] + p.c1[p.bm[row] * HH + col]) * p.dinv[row];
            p.bufA[row * HH + col] = v;
        }
    }
    grid.sync();

    // ================= P4: conv1 agg + gemm2 (wave per dst row) =================
    {
        int w = t >> 6, l = t & 63;
        int dst = b * 4 + w;
        const float2* xwp = (const float2*)p.bufA;
        float2 acc = xwp[dst * 64 + l];  // self loop, pre-scaled
        int beg = p.row_ptr[dst], end = p.row_ptr[dst + 1];
        int e = beg;
        for (; e + 3 < end; e += 4) {
            int s0 = p.col_idx[e], s1 = p.col_idx[e + 1], s2 = p.col_idx[e + 2], s3 = p.col_idx[e + 3];
            float2 v0 = xwp[s0 * 64 + l], v1 = xwp[s1 * 64 + l];
            float2 v2 = xwp[s2 * 64 + l], v3 = xwp[s3 * 64 + l];
            acc.x += (v0.x + v1.x) + (v2.x + v3.x);
            acc.y += (v0.y + v1.y) + (v2.y + v3.y);
        }
        for (; e < end; e++) {
            float2 v = xwp[p.col_idx[e] * 64 + l];
            acc.x += v.x;
            acc.y += v.y;
        }
        float dd = p.dinv[dst];
        float2 h;
        h.x = fmaxf(dd * acc.x + p.b1[2 * l], 0.f);
        h.y = fmaxf(dd * acc.y + p.b1[2 * l + 1], 0.f);
        float* hr = sm;  // 4 rows x 128
        *(float2*)&hr[w * HH + 2 * l] = h;
        __syncthreads();
        float2 o = {0.f, 0.f};
#pragma unroll 4
        for (int k = 0; k < HH; k++) {
            float hk = hr[w * HH + k];
            float2 wv = *(const float2*)&p.Wc2[k * HH + 2 * l];
            o.x += hk * wv.x;
            o.y += hk * wv.y;
        }
        o.x *= dd;
        o.y *= dd;
        ((float2*)p.bufB)[dst * 64 + l] = o;
    }
    grid.sync();

    // ================= P5: conv2 agg + pred + sl/sr =================
    {
        int w = t >> 6, l = t & 63;
        int dst = b * 4 + w;
        const float2* xwp = (const float2*)p.bufB;
        float2 acc = xwp[dst * 64 + l];
        int beg = p.row_ptr[dst], end = p.row_ptr[dst + 1];
        int e = beg;
        for (; e + 3 < end; e += 4) {
            int s0 = p.col_idx[e], s1 = p.col_idx[e + 1], s2 = p.col_idx[e + 2], s3 = p.col_idx[e + 3];
            float2 v0 = xwp[s0 * 64 + l], v1 = xwp[s1 * 64 + l];
            float2 v2 = xwp[s2 * 64 + l], v3 = xwp[s3 * 64 + l];
            acc.x += (v0.x + v1.x) + (v2.x + v3.x);
            acc.y += (v0.y + v1.y) + (v2.y + v3.y);
        }
        for (; e < end; e++) {
            float2 v = xwp[p.col_idx[e] * 64 + l];
            acc.x += v.x;
            acc.y += v.y;
        }
        float dd = p.dinv[dst];
        float2 h;
        h.x = fmaxf(dd * acc.x + p.b2[2 * l], 0.f);
        h.y = fmaxf(dd * acc.y + p.b2[2 * l + 1], 0.f);
        float* hr = sm;
        __syncthreads();  // sm reuse: all P4 reads done before overwrite
        *(float2*)&hr[w * HH + 2 * l] = h;
        __syncthreads();
        {
            int c = l & 15, q = l >> 4;
            float a = 0.f;
#pragma unroll 4
            for (int k = q * 32; k < q * 32 + 32; k++) a += hr[w * HH + k] * p.Wo[k * NDD + c];
            a += __shfl_xor(a, 16);
            a += __shfl_xor(a, 32);
            if (q == 0) p.out_pred[dst * NDD + c] = a + p.bo[c];
        }
        {
            float h0 = hr[w * HH + l], h1v = hr[w * HH + 64 + l];
            float pl = h0 * p.we[l] + h1v * p.we[64 + l];
            float pr = h0 * p.we[HH + l] + h1v * p.we[HH + 64 + l];
            for (int off = 32; off; off >>= 1) {
                pl += __shfl_down(pl, off);
                pr += __shfl_down(pr, off);
            }
            if (l == 0) {
                p.sl[dst] = pl;
                p.sr[dst] = pr;
            }
        }
    }
    grid.sync();

    // ================= P6: edge logits (grid-stride over 2048 row-pairs) =================
    {
        float be = p.be[0];
        for (int bb = b; bb < NN / 2; bb += GRID) {
#pragma unroll
            for (int half = 0; half < 2; half++) {
                int r = half == 0 ? bb : (NN - 2 - bb);
                int off = r * (2 * NN - r - 1) / 2;  // < 2^23, fits int
                int len = NN - 1 - r;
                float s = p.sl[r] + be;
                const float* sp = p.sr + r + 1;
                float* op = p.out_edges + off;
                int hd = (4 - (off & 3)) & 3;
                if (hd > len) hd = len;
                if (t < hd) __builtin_nontemporal_store(s + sp[t], op + t);
                int body = (len - hd) >> 2;
                float* opb = op + hd;
                const float* spb = sp + hd;
                for (int i = t; i < body; i += 256) {
                    int base = 4 * i;
                    nt_f4 v;
                    v.x = s + spb[base];
                    v.y = s + spb[base + 1];
                    v.z = s + spb[base + 2];
                    v.w = s + spb[base + 3];
                    __builtin_nontemporal_store(v, (nt_f4*)(opb + base));
                }
                int tail = hd + body * 4;
                int rem = len - tail;
                if (t < rem) __builtin_nontemporal_store(s + sp[tail + t], op + tail + t);
            }
        }
    }
}

extern "C" void kernel_launch(void* const* d_in, const int* in_sizes, int n_in,
                              void* d_out, int out_size, void* d_ws, size_t ws_size,
                              hipStream_t stream) {
    Prm p;
    p.x = (const float*)d_in[0];
    p.e_src = (const int*)d_in[1];
    p.e_dst = ((const int*)d_in[1]) + EE;
    p.timestep = (const int*)d_in[2];
    p.bm = (const int*)d_in[3];
    p.nuc = (const int*)d_in[4];
    p.central = (const int*)d_in[5];
    p.backbone = (const int*)d_in[6];
    p.obj_x = (const float*)d_in[7];
    p.obj_pos = (const float*)d_in[8];
    p.obj_batch = (const int*)d_in[9];
    p.Wn = (const float*)d_in[10];
    p.bn = (const float*)d_in[11];
    p.Wc = (const float*)d_in[12];
    p.bc = (const float*)d_in[13];
    p.Wt = (const float*)d_in[14];
    p.bt = (const float*)d_in[15];
    p.Wc1 = (const float*)d_in[16];
    p.b1 = (const float*)d_in[17];
    p.Wc2 = (const float*)d_in[18];
    p.b2 = (const float*)d_in[19];
    p.Wo = (const float*)d_in[20];
    p.bo = (const float*)d_in[21];
    p.we = (const float*)d_in[22];
    p.be = (const float*)d_in[23];

    float* ws = (float*)d_ws;
    p.bufA = ws;                                  // N*H (xw1')
    p.bufB = p.bufA + NN * HH;                    // N*H (xw2')
    p.W1p = p.bufB + NN * HH;                     // 16*H
    p.c1 = p.W1p + NDD * HH;                      // G*H
    p.partial = p.c1 + GG * HH;                   // CBLK*G*16
    p.pcnt = p.partial + CBLK * GG * NDD;         // CBLK*G
    p.dinv = p.pcnt + CBLK * GG;                  // N
    p.sl = p.dinv + NN;                           // N
    p.sr = p.sl + NN;                             // N
    p.deg = (int*)(p.sr + NN);                    // N
    p.row_ptr = p.deg + NN;                       // N+1
    p.cursor = p.row_ptr + NN + 1;                // N
    p.col_idx = p.cursor + NN;                    // E

    p.out_pred = (float*)d_out;
    p.out_edges = p.out_pred + NN * NDD;

    void* args[] = {&p};
    (void)hipLaunchCooperativeKernel((const void*)mega, dim3(GRID), dim3(256),
                                     args, 0, stream);
}

// Round 7
// 212.912 us; speedup vs baseline: 4.2377x; 4.2377x over previous
//
#include <hip/hip_runtime.h>

#define NN 4096
#define MM 8192
#define GG 8
#define HH 128
#define NDD 16
#define EE 131072
#define CBLK 64            // cond partial blocks
#define COBJ (MM / CBLK)   // 128 objects per cond block
#define HBLK 16            // deg-histogram blocks
#define HEDGE (EE / HBLK)  // 8192 edges per hist block

typedef float nt_f4 __attribute__((ext_vector_type(4)));

// ============ K1 front: cond partials (0..63) | deg LDS-hist (64..79) | W1p (80) ============
__global__ __launch_bounds__(256) void k_front(
    const float* __restrict__ obj_x, const float* __restrict__ obj_pos,
    const int* __restrict__ nuc, const int* __restrict__ central,
    const int* __restrict__ backbone, const int* __restrict__ obj_batch,
    const int* __restrict__ e_dst, int* __restrict__ phist,
    float* __restrict__ partial, float* __restrict__ pcnt,
    const float* __restrict__ Wn, const float* __restrict__ Wc1,
    float* __restrict__ W1p) {
    int b = blockIdx.x, t = threadIdx.x;
    if (b < CBLK) {
        // cond: pool 16-dim inputs. d = t&15, oi = t>>4 (16 objs parallel, 8 passes)
        __shared__ float ls[GG * NDD];
        __shared__ float lc[GG];
        if (t < GG * NDD) ls[t] = 0.f;
        if (t < GG) lc[t] = 0.f;
        __syncthreads();
        int d = t & 15, oi = t >> 4;
        int base = b * COBJ;
#pragma unroll
        for (int pass = 0; pass < COBJ / 16; pass++) {
            int o = base + pass * 16 + oi;
            int nv = nuc[o];
            bool isb = (backbone[o] == 0);
            bool cond = (nv == 0) || ((central[o] != 0) && isb) || ((nv == 2) && isb);
            if (cond) {
                float v = (d < 13) ? obj_x[o * 13 + d] : obj_pos[o * 3 + (d - 13)];
                int g = obj_batch[o];
                atomicAdd(&ls[g * NDD + d], v);
                if (d == 0) atomicAdd(&lc[g], 1.f);
            }
        }
        __syncthreads();
        if (t < GG * NDD) partial[b * (GG * NDD) + t] = ls[t];
        if (t < GG) pcnt[b * GG + t] = lc[t];
        return;
    }
    if (b < CBLK + HBLK) {
        // degree histogram for edge chunk hb (LDS atomics, partial written out)
        int hb = b - CBLK;
        __shared__ int hist[NN];
        for (int i = t; i < NN; i += 256) hist[i] = 0;
        __syncthreads();
        const int4* ed4 = ((const int4*)e_dst) + hb * (HEDGE / 4);
        for (int i = t; i < HEDGE / 4; i += 256) {
            int4 d4 = ed4[i];
            atomicAdd(&hist[d4.x], 1);
            atomicAdd(&hist[d4.y], 1);
            atomicAdd(&hist[d4.z], 1);
            atomicAdd(&hist[d4.w], 1);
        }
        __syncthreads();
        int4* ph4 = (int4*)(phist + hb * NN);
        for (int i = t; i < NN / 4; i += 256) ph4[i] = ((int4*)hist)[i];
        return;
    }
    // W1'[a][j] = sum_k Wn[a][k] * Wc1[k][j]
    int j = t & 127, a0 = t >> 7;
#pragma unroll
    for (int ai = 0; ai < 8; ai++) {
        int a = a0 + 2 * ai;
        float acc = 0.f;
        for (int k = 0; k < HH; k++) acc += Wn[a * HH + k] * Wc1[k * HH + j];
        W1p[a * HH + j] = acc;
    }
}

// ============ K2 mid: c1 (block 0) | scan (block 1) | xw1_partial (2..129) ============
__global__ __launch_bounds__(1024) void k_mid(
    const int* __restrict__ timestep, const float* __restrict__ partial,
    const float* __restrict__ pcnt, const float* __restrict__ Wn,
    const float* __restrict__ bn, const float* __restrict__ Wt,
    const float* __restrict__ bt, const float* __restrict__ Wc,
    const float* __restrict__ bc, const float* __restrict__ Wc1,
    float* __restrict__ c1, const int* __restrict__ phist,
    int* __restrict__ row_ptr, int* __restrict__ cursor,
    float* __restrict__ dinv, const float* __restrict__ x,
    const float* __restrict__ W1p, float* __restrict__ xw) {
    int b = blockIdx.x, t = threadIdx.x;
    if (b == 0) {
        // ---- c1 = (bn + time_h + cond_h) @ Wc1 ----
        __shared__ float s16[GG * NDD];
        __shared__ float cinv[GG];
        __shared__ float te[GG * HH];
        __shared__ float pool[GG * HH];
        __shared__ float v2[GG * HH];
        int g = t >> 7, j = t & 127;
        if (t < GG * NDD) {
            float s = 0.f;
            for (int q = 0; q < CBLK; q++) s += partial[q * (GG * NDD) + t];
            s16[t] = s;
        }
        if (t < GG) {
            float c = 0.f;
            for (int q = 0; q < CBLK; q++) c += pcnt[q * GG + t];
            cinv[t] = 1.f / fmaxf(c, 1.f);
        }
        // timestep embedding
        float tv = (float)timestep[g];
        float val;
        if (j < 64) {
            float f = expf(-logf(10000.f) * (float)j / 64.f);
            val = cosf(tv * f);
        } else {
            float f = expf(-logf(10000.f) * (float)(j - 64) / 64.f);
            val = sinf(tv * f);
        }
        te[t] = val;
        __syncthreads();
        float p = bn[j];
#pragma unroll
        for (int d = 0; d < NDD; d++) p += s16[g * NDD + d] * cinv[g] * Wn[d * HH + j];
        pool[t] = p;
        __syncthreads();
        float acc = bt[j] + bc[j] + bn[j];
        for (int k = 0; k < HH; k++) {
            acc += te[g * HH + k] * Wt[k * HH + j] + pool[g * HH + k] * Wc[k * HH + j];
        }
        v2[t] = acc;
        __syncthreads();
        float cc = 0.f;
        for (int k = 0; k < HH; k++) cc += v2[g * HH + k] * Wc1[k * HH + j];
        c1[t] = cc;
    } else if (b == 1) {
        // ---- scan: deg = sum of 16 hist partials, then exclusive scan ----
        __shared__ int aux[1024];
        int4 d4 = {0, 0, 0, 0};
        const int4* ph4 = (const int4*)phist;
#pragma unroll
        for (int h = 0; h < HBLK; h++) {
            int4 v = ph4[h * (NN / 4) + t];
            d4.x += v.x; d4.y += v.y; d4.z += v.z; d4.w += v.w;
        }
        int s = d4.x + d4.y + d4.z + d4.w;
        aux[t] = s;
        __syncthreads();
        for (int off = 1; off < 1024; off <<= 1) {
            int v = (t >= off) ? aux[t - off] : 0;
            __syncthreads();
            aux[t] += v;
            __syncthreads();
        }
        int run = (t > 0) ? aux[t - 1] : 0;
        int d[4] = {d4.x, d4.y, d4.z, d4.w};
#pragma unroll
        for (int i = 0; i < 4; i++) {
            int idx = t * 4 + i;
            row_ptr[idx] = run;
            cursor[idx] = run;
            dinv[idx] = rsqrtf((float)(d[i] + 1));  // +1: self loop
            run += d[i];
        }
        if (t == 1023) row_ptr[NN] = run;
    } else {
        // ---- xw1_partial = x @ W1p (32 rows per block) ----
        __shared__ float xt[32 * NDD];
        int r0 = (b - 2) * 32;
        if (t < 512) xt[t] = x[r0 * NDD + t];
        __syncthreads();
        int col = t & 127, rh = t >> 7;  // rh 0..7
        float acc[4] = {0.f, 0.f, 0.f, 0.f};
#pragma unroll
        for (int k = 0; k < NDD; k++) {
            float w = W1p[k * HH + col];
#pragma unroll
            for (int i = 0; i < 4; i++) acc[i] += xt[(rh * 4 + i) * NDD + k] * w;
        }
#pragma unroll
        for (int i = 0; i < 4; i++) xw[(r0 + rh * 4 + i) * HH + col] = acc[i];
    }
}

// ============ K3: scatter int4 (0..127) + xw1 fixup (+c1[bm])*dinv (128..639) ============
__global__ __launch_bounds__(256) void k_scatfix(
    const int* __restrict__ e_src, const int* __restrict__ e_dst,
    int* __restrict__ cursor, int* __restrict__ col_idx,
    const float* __restrict__ c1, const int* __restrict__ bm,
    const float* __restrict__ dinv, float* __restrict__ xw) {
    int b = blockIdx.x, t = threadIdx.x;
    if (b < 128) {
        int i4 = b * 256 + t;
        int4 d4 = ((const int4*)e_dst)[i4];
        int4 s4 = ((const int4*)e_src)[i4];
        int p;
        p = atomicAdd(&cursor[d4.x], 1); col_idx[p] = s4.x;
        p = atomicAdd(&cursor[d4.y], 1); col_idx[p] = s4.y;
        p = atomicAdd(&cursor[d4.z], 1); col_idx[p] = s4.z;
        p = atomicAdd(&cursor[d4.w], 1); col_idx[p] = s4.w;
        return;
    }
    int r0 = (b - 128) * 8;
    int col = t & 127, rh = t >> 7;
#pragma unroll
    for (int i = 0; i < 4; i++) {
        int row = r0 + rh * 4 + i;
        xw[row * HH + col] = (xw[row * HH + col] + c1[bm[row] * HH + col]) * dinv[row];
    }
}

// ============ K4: conv1 aggregate + fused gemm2. One 64-lane wave per dst row. ============
__global__ __launch_bounds__(256) void k_conv1(
    const float* __restrict__ xw, const int* __restrict__ row_ptr,
    const int* __restrict__ col_idx, const float* __restrict__ dinv,
    const float* __restrict__ b1, const float* __restrict__ Wc2,
    float* __restrict__ xw2) {
    int w = threadIdx.x >> 6, l = threadIdx.x & 63;
    int dst = blockIdx.x * 4 + w;
    const float2* xwp = (const float2*)xw;
    float2 acc = xwp[dst * 64 + l];  // self loop, pre-scaled
    int beg = row_ptr[dst], end = row_ptr[dst + 1];
    int e = beg;
    for (; e + 3 < end; e += 4) {
        int s0 = col_idx[e], s1 = col_idx[e + 1], s2 = col_idx[e + 2], s3 = col_idx[e + 3];
        float2 v0 = xwp[s0 * 64 + l], v1 = xwp[s1 * 64 + l];
        float2 v2 = xwp[s2 * 64 + l], v3 = xwp[s3 * 64 + l];
        acc.x += (v0.x + v1.x) + (v2.x + v3.x);
        acc.y += (v0.y + v1.y) + (v2.y + v3.y);
    }
    for (; e < end; e++) {
        float2 v = xwp[col_idx[e] * 64 + l];
        acc.x += v.x;
        acc.y += v.y;
    }
    float dd = dinv[dst];
    float2 h;
    h.x = fmaxf(dd * acc.x + b1[2 * l], 0.f);
    h.y = fmaxf(dd * acc.y + b1[2 * l + 1], 0.f);
    __shared__ float hr[4][HH];
    *(float2*)&hr[w][2 * l] = h;
    __syncthreads();
    float2 o = {0.f, 0.f};
#pragma unroll 4
    for (int k = 0; k < HH; k++) {
        float hk = hr[w][k];
        float2 wv = *(const float2*)&Wc2[k * HH + 2 * l];
        o.x += hk * wv.x;
        o.y += hk * wv.y;
    }
    o.x *= dd;
    o.y *= dd;
    ((float2*)xw2)[dst * 64 + l] = o;
}

// ============ K5: conv2 aggregate + pred + sl/sr. One wave per dst row. ============
__global__ __launch_bounds__(256) void k_conv2_head(
    const float* __restrict__ xw, const int* __restrict__ row_ptr,
    const int* __restrict__ col_idx, const float* __restrict__ dinv,
    const float* __restrict__ b2, const float* __restrict__ Wo,
    const float* __restrict__ bo, const float* __restrict__ we,
    float* __restrict__ out_pred, float* __restrict__ sl, float* __restrict__ sr) {
    int w = threadIdx.x >> 6, l = threadIdx.x & 63;
    int dst = blockIdx.x * 4 + w;
    const float2* xwp = (const float2*)xw;
    float2 acc = xwp[dst * 64 + l];
    int beg = row_ptr[dst], end = row_ptr[dst + 1];
    int e = beg;
    for (; e + 3 < end; e += 4) {
        int s0 = col_idx[e], s1 = col_idx[e + 1], s2 = col_idx[e + 2], s3 = col_idx[e + 3];
        float2 v0 = xwp[s0 * 64 + l], v1 = xwp[s1 * 64 + l];
        float2 v2 = xwp[s2 * 64 + l], v3 = xwp[s3 * 64 + l];
        acc.x += (v0.x + v1.x) + (v2.x + v3.x);
        acc.y += (v0.y + v1.y) + (v2.y + v3.y);
    }
    for (; e < end; e++) {
        float2 v = xwp[col_idx[e] * 64 + l];
        acc.x += v.x;
        acc.y += v.y;
    }
    float dd = dinv[dst];
    float2 h;
    h.x = fmaxf(dd * acc.x + b2[2 * l], 0.f);
    h.y = fmaxf(dd * acc.y + b2[2 * l + 1], 0.f);
    __shared__ float hr[4][HH];
    *(float2*)&hr[w][2 * l] = h;
    __syncthreads();
    // pred: c = l&15, partial p = l>>4 over k in [32p, 32p+32)
    {
        int c = l & 15, p = l >> 4;
        float a = 0.f;
#pragma unroll 4
        for (int k = p * 32; k < p * 32 + 32; k++) a += hr[w][k] * Wo[k * NDD + c];
        a += __shfl_xor(a, 16);
        a += __shfl_xor(a, 32);
        if (p == 0) out_pred[dst * NDD + c] = a + bo[c];
    }
    // sl/sr
    {
        float h0 = hr[w][l], h1v = hr[w][64 + l];
        float pl = h0 * we[l] + h1v * we[64 + l];
        float pr = h0 * we[HH + l] + h1v * we[HH + 64 + l];
        for (int off = 32; off; off >>= 1) {
            pl += __shfl_down(pl, off);
            pr += __shfl_down(pr, off);
        }
        if (l == 0) {
            sl[dst] = pl;
            sr[dst] = pr;
        }
    }
}

// ============ K6: edge logits, nontemporal stores, rows b and NN-2-b per block ============
__global__ __launch_bounds__(256) void k_edges(const float* __restrict__ sl,
                                               const float* __restrict__ sr,
                                               const float* __restrict__ be_p,
                                               float* __restrict__ out) {
    int b = blockIdx.x, t = threadIdx.x;
    float be = be_p[0];
#pragma unroll
    for (int half = 0; half < 2; half++) {
        int r = half == 0 ? b : (NN - 2 - b);
        int off = r * (2 * NN - r - 1) / 2;  // < 2^23, fits int
        int len = NN - 1 - r;
        float s = sl[r] + be;
        const float* sp = sr + r + 1;
        float* op = out + off;
        int hd = (4 - (off & 3)) & 3;
        if (hd > len) hd = len;
        if (t < hd) __builtin_nontemporal_store(s + sp[t], op + t);
        int body = (len - hd) >> 2;
        float* opb = op + hd;
        const float* spb = sp + hd;
        for (int i = t; i < body; i += 256) {
            int base = 4 * i;
            nt_f4 v;
            v.x = s + spb[base];
            v.y = s + spb[base + 1];
            v.z = s + spb[base + 2];
            v.w = s + spb[base + 3];
            __builtin_nontemporal_store(v, (nt_f4*)(opb + base));
        }
        int tail = hd + body * 4;
        int rem = len - tail;
        if (t < rem) __builtin_nontemporal_store(s + sp[tail + t], op + tail + t);
    }
}

extern "C" void kernel_launch(void* const* d_in, const int* in_sizes, int n_in,
                              void* d_out, int out_size, void* d_ws, size_t ws_size,
                              hipStream_t stream) {
    const float* x = (const float*)d_in[0];
    const int* e_src = (const int*)d_in[1];
    const int* e_dst = e_src + EE;
    const int* timestep = (const int*)d_in[2];
    const int* batch_map = (const int*)d_in[3];
    const int* nuc = (const int*)d_in[4];
    const int* central = (const int*)d_in[5];
    const int* backbone = (const int*)d_in[6];
    const float* obj_x = (const float*)d_in[7];
    const float* obj_pos = (const float*)d_in[8];
    const int* obj_batch = (const int*)d_in[9];
    const float* W_node = (const float*)d_in[10];
    const float* b_node = (const float*)d_in[11];
    const float* W_cond = (const float*)d_in[12];
    const float* b_cond = (const float*)d_in[13];
    const float* W_time = (const float*)d_in[14];
    const float* b_time = (const float*)d_in[15];
    const float* W_conv1 = (const float*)d_in[16];
    const float* b_conv1 = (const float*)d_in[17];
    const float* W_conv2 = (const float*)d_in[18];
    const float* b_conv2 = (const float*)d_in[19];
    const float* W_out = (const float*)d_in[20];
    const float* b_out = (const float*)d_in[21];
    const float* w_edge = (const float*)d_in[22];
    const float* b_edge = (const float*)d_in[23];

    // workspace
    float* ws = (float*)d_ws;
    float* bufA = ws;                        // N*H (xw1')
    float* bufB = bufA + NN * HH;            // N*H (xw2')
    float* W1p = bufB + NN * HH;             // 16*H
    float* c1 = W1p + NDD * HH;              // G*H
    float* partial = c1 + GG * HH;           // CBLK*G*16
    float* pcnt = partial + CBLK * GG * NDD; // CBLK*G
    float* dinv = pcnt + CBLK * GG;          // N
    float* sl = dinv + NN;                   // N
    float* sr = sl + NN;                     // N
    int* phist = (int*)(sr + NN);            // HBLK*N
    int* row_ptr = phist + HBLK * NN;        // N+1
    int* cursor = row_ptr + NN + 1;          // N
    int* col_idx = cursor + NN;              // E

    float* out_pred = (float*)d_out;
    float* out_edges = out_pred + NN * NDD;

    // K1: cond partials + deg histograms + W1p  (no memset needed)
    k_front<<<CBLK + HBLK + 1, 256, 0, stream>>>(obj_x, obj_pos, nuc, central,
                                                 backbone, obj_batch, e_dst, phist,
                                                 partial, pcnt, W_node, W_conv1, W1p);
    // K2: c1 + scan + xw1_partial
    k_mid<<<2 + NN / 32, 1024, 0, stream>>>(timestep, partial, pcnt, W_node, b_node,
                                            W_time, b_time, W_cond, b_cond, W_conv1,
                                            c1, phist, row_ptr, cursor, dinv, x, W1p,
                                            bufA);
    // K3: scatter + fixup
    k_scatfix<<<128 + 512, 256, 0, stream>>>(e_src, e_dst, cursor, col_idx, c1,
                                             batch_map, dinv, bufA);
    // K4: conv1 agg + gemm2 -> xw2'
    k_conv1<<<NN / 4, 256, 0, stream>>>(bufA, row_ptr, col_idx, dinv, b_conv1,
                                        W_conv2, bufB);
    // K5: conv2 agg + pred + sl/sr
    k_conv2_head<<<NN / 4, 256, 0, stream>>>(bufB, row_ptr, col_idx, dinv, b_conv2,
                                             W_out, b_out, w_edge, out_pred, sl, sr);
    // K6: edge logits
    k_edges<<<NN / 2, 256, 0, stream>>>(sl, sr, b_edge, out_edges);
}